// Round 2
// baseline (399.762 us; speedup 1.0000x reference)
//
#include <hip/hip_runtime.h>

#define N_NODES 100000
#define N_EDGES 1600000
#define B_GRAPHS 64
#define BN_EPS 1e-5
#define NBMAX 3200    // max per-layer stats-partial blocks (L3 uses 1563)

#define NBS 391       // cdiv(N_NODES, 256) — node-scan blocks

#define QSCALE 2048.0f            // 2^11 int16 fixed-point scale
#define QINV   4.8828125e-4f      // 2^-11

typedef _Float16 half4_t __attribute__((ext_vector_type(4)));
typedef short short4_t __attribute__((ext_vector_type(4)));
typedef int intv2 __attribute__((ext_vector_type(2)));
typedef int intv4 __attribute__((ext_vector_type(4)));
typedef float floatv4 __attribute__((ext_vector_type(4)));

static inline int cdiv(long long a, int b) { return (int)((a + b - 1) / b); }

__device__ __forceinline__ short q16(float v) {
    int q = __float2int_rn(v * QSCALE);
    q = q > 32767 ? 32767 : (q < -32768 ? -32768 : q);
    return (short)q;
}

// ---------------- CSR build, direct global-atomic version ----------------
// deg histogram: one int4-vectorized pass over col. 1.6M atomics spread over
// 100K counters (avg 16 hits) -> memory-side atomics, negligible contention.
__global__ void deg_hist_kernel(const int* __restrict__ col, int* __restrict__ deg) {
    int t = blockIdx.x * blockDim.x + threadIdx.x;
    if (t >= N_EDGES / 4) return;
    intv4 c = ((const intv4*)col)[t];
    atomicAdd(&deg[c[0]], 1);
    atomicAdd(&deg[c[1]], 1);
    atomicAdd(&deg[c[2]], 1);
    atomicAdd(&deg[c[3]], 1);
}

// per-256-node block sums of deg
__global__ void bsum_kernel(const int* __restrict__ deg, int* __restrict__ bsum) {
    __shared__ int s[256];
    int b = blockIdx.x, t = threadIdx.x;
    int n = b * 256 + t;
    s[t] = (n < N_NODES) ? deg[n] : 0;
    __syncthreads();
    for (int off = 128; off > 0; off >>= 1) {
        if (t < off) s[t] += s[t + off];
        __syncthreads();
    }
    if (t == 0) bsum[b] = s[0];
}

// single-block exclusive scan of the 391 block sums
__global__ void bscan_kernel(const int* __restrict__ bsum, int* __restrict__ bbase) {
    __shared__ int s[512];
    int t = threadIdx.x;
    int v = (t < NBS) ? bsum[t] : 0;
    s[t] = v;
    __syncthreads();
    for (int off = 1; off < 512; off <<= 1) {
        int u = (t >= off) ? s[t - off] : 0;
        __syncthreads();
        s[t] += u;
        __syncthreads();
    }
    if (t < NBS) bbase[t] = s[t] - v;  // exclusive
}

// per-block LDS scan -> row_ptr & scatter cursor; fused dis + scale_x (int16 fxp, pad 3->4)
__global__ void csr_apply_kernel(const int* __restrict__ deg, const int* __restrict__ bbase,
                                 int* __restrict__ row_ptr, int* __restrict__ cursor,
                                 float* __restrict__ dis, const float* __restrict__ x,
                                 short* __restrict__ xs4) {
    __shared__ int tsum[256];
    int b = blockIdx.x, t = threadIdx.x;
    int n = b * 256 + t;
    int v = (n < N_NODES) ? deg[n] : 0;
    tsum[t] = v;
    __syncthreads();
    for (int off = 1; off < 256; off <<= 1) {
        int u = (t >= off) ? tsum[t - off] : 0;
        __syncthreads();
        tsum[t] += u;
        __syncthreads();
    }
    if (n < N_NODES) {
        int rp = bbase[b] + tsum[t] - v;
        row_ptr[n] = rp;
        cursor[n] = rp;
        float d = rsqrtf((float)v + 1.0f);
        dis[n] = d;
        short4_t q;
        q.x = q16(x[n * 3 + 0] * d);
        q.y = q16(x[n * 3 + 1] * d);
        q.z = q16(x[n * 3 + 2] * d);
        q.w = 0;
        ((short4_t*)xs4)[n] = q;
    }
}

// scatter edges into CSR slots via fetch-add cursors. Order within a node's
// segment is nondeterministic -> harmless: downstream sums are pure-int.
__global__ void scatter_kernel(const int* __restrict__ row, const int* __restrict__ col,
                               int* __restrict__ cursor, int* __restrict__ sorted_row) {
    int t = blockIdx.x * blockDim.x + threadIdx.x;
    if (t >= N_EDGES / 4) return;
    intv4 r = ((const intv4*)row)[t];
    intv4 c = ((const intv4*)col)[t];
#pragma unroll
    for (int k = 0; k < 4; k++) {
        int p = atomicAdd(&cursor[c[k]], 1);
        sorted_row[p] = r[k];
    }
}

// ---------------- FUSED: CSR gather (16B int16 vector loads, pure-int accumulation)
//                  -> LDS -> matmul (W in regs, b128 broadcast agg reads) -> fp16 pre + fp64 stats
// Activations stored pre-quantized int16; integer accumulation -> order-independent (deterministic).
// WPL = 32-bit words per lane of gather payload (2 -> int2/8B, 4 -> int4/16B).
template <int WPL> struct VecSel;
template <> struct VecSel<2> { using type = intv2; };
template <> struct VecSel<4> { using type = intv4; };

template <int IN, int OUT, int INSTRIDE, int WPL>
__global__ void gather_mm_kernel(const int* __restrict__ row_ptr, const int* __restrict__ deg,
                                 const int* __restrict__ sorted_row, const float* __restrict__ dis,
                                 const short* __restrict__ hs, const float* __restrict__ W,
                                 const float* __restrict__ b, _Float16* __restrict__ pre,
                                 double* __restrict__ part_s, double* __restrict__ part_q) {
    using V = typename VecSel<WPL>::type;
    const int FPL = 2 * WPL;          // int16 features per lane
    const int LPN = INSTRIDE / FPL;   // lanes per node (L1:1, L2:2, L3:4)
    const int NPW = 64 / LPN;         // nodes per wave
    const int NPB = 4 * NPW;          // nodes per block (L1:256, L2:128, L3:64)
    const int UNROLL = (WPL == 4) ? 4 : 8;  // keep ~64B in flight/lane, VGPR < 64
    __shared__ __align__(16) float lds_agg[NPB * INSTRIDE];
    __shared__ double s_s[256];
    __shared__ double s_q[256];
    int tid = threadIdx.x;
    int wv = tid >> 6, lane = tid & 63;
    int jn = wv * NPW + lane / LPN;   // node index within block
    int p = lane % LPN;               // feature-slice index
    int n = blockIdx.x * NPB + jn;
    if (n < N_NODES) {
        int start = row_ptr[n];
        int d = deg[n];
        const int* sr = sorted_row + start;
        const V* hv = (const V*)hs;
        V v = hv[n * LPN + p];        // self-loop term; 32-bit index (fits: N*LPN < 2^31)
        int acc[FPL];
#pragma unroll
        for (int w = 0; w < WPL; w++) {
            acc[2 * w] = (int)(short)v[w];
            acc[2 * w + 1] = v[w] >> 16;
        }
        int j = 0;
        for (; j + UNROLL <= d; j += UNROLL) {
            V a[UNROLL];
#pragma unroll
            for (int u = 0; u < UNROLL; u++) a[u] = hv[sr[j + u] * LPN + p];
#pragma unroll
            for (int u = 0; u < UNROLL; u++) {
#pragma unroll
                for (int w = 0; w < WPL; w++) {
                    acc[2 * w] += (int)(short)a[u][w];
                    acc[2 * w + 1] += a[u][w] >> 16;
                }
            }
        }
        for (; j < d; j++) {
            V a = hv[sr[j] * LPN + p];
#pragma unroll
            for (int w = 0; w < WPL; w++) {
                acc[2 * w] += (int)(short)a[w];
                acc[2 * w + 1] += a[w] >> 16;
            }
        }
        float dn = dis[n] * QINV;
        float* dst = &lds_agg[(jn * LPN + p) * FPL];  // 16B/32B aligned -> ds_write_b128
#pragma unroll
        for (int k = 0; k < FPL; k++) dst[k] = dn * (float)acc[k];
    }
    __syncthreads();

    // ---- matmul + stats phase (deterministic: fixed order over deterministic agg)
    // W column held in registers (coalesced global loads, L2-hot); lds_agg read as
    // wave-uniform float4 broadcasts -> ~5x fewer LDS ops than scalar form.
    const int NG = 256 / OUT;  // node groups
    int o = tid % OUT;
    int g = tid / OUT;
    float wreg[IN];
#pragma unroll
    for (int k = 0; k < IN; k++) wreg[k] = W[k * OUT + o];
    float bo = b[o];
    double my_s = 0.0, my_q = 0.0;
    for (int j2 = g; j2 < NPB; j2 += NG) {
        int nn = blockIdx.x * NPB + j2;
        if (nn < N_NODES) {
            float acc = bo;
            const floatv4* src = (const floatv4*)&lds_agg[j2 * INSTRIDE];
#pragma unroll
            for (int q = 0; q < INSTRIDE / 4; q++) {
                floatv4 vq = src[q];
#pragma unroll
                for (int c = 0; c < 4; c++) {
                    if (4 * q + c < IN) acc += vq[c] * wreg[4 * q + c];
                }
            }
            _Float16 hq = (_Float16)acc;
            pre[nn * OUT + o] = hq;
            float fq = (float)hq;  // stats on quantized values
            my_s += (double)fq;
            my_q += (double)fq * (double)fq;
        }
    }
    s_s[tid] = my_s;
    s_q[tid] = my_q;
    __syncthreads();
    if (tid < OUT) {
        double ts = 0.0, tq = 0.0;
        for (int k = tid; k < 256; k += OUT) { ts += s_s[k]; tq += s_q[k]; }
        part_s[(long long)tid * NBMAX + blockIdx.x] = ts;
        part_q[(long long)tid * NBMAX + blockIdx.x] = tq;
    }
}

// ---------------- finalize BN stats: one block per feature, variable #partials ----------------
__global__ void bn_finalize_kernel(const double* __restrict__ part_s, const double* __restrict__ part_q,
                                   int nb, float* __restrict__ bn_mean, float* __restrict__ bn_rstd) {
    __shared__ double s_s[256];
    __shared__ double s_q[256];
    int o = blockIdx.x;
    int t = threadIdx.x;
    double ms = 0.0, mq = 0.0;
    for (int k = t; k < nb; k += 256) {
        ms += part_s[(long long)o * NBMAX + k];
        mq += part_q[(long long)o * NBMAX + k];
    }
    s_s[t] = ms;
    s_q[t] = mq;
    __syncthreads();
    for (int off = 128; off > 0; off >>= 1) {
        if (t < off) { s_s[t] += s_s[t + off]; s_q[t] += s_q[t + off]; }
        __syncthreads();
    }
    if (t == 0) {
        double mean = s_s[0] / (double)N_NODES;
        double var = s_q[0] / (double)N_NODES - mean * mean;
        bn_mean[o] = (float)mean;
        bn_rstd[o] = (float)(1.0 / sqrt(var + BN_EPS));
    }
}

// ---------------- BN apply + ReLU + dis pre-scale; fp16 in, INT16 fixed-point out ----------------
template <int F>
__global__ void bn_relu_kernel(const _Float16* __restrict__ pre, const float* __restrict__ bn_mean,
                               const float* __restrict__ bn_rstd, const float* __restrict__ g,
                               const float* __restrict__ be, const float* __restrict__ dis,
                               short* __restrict__ out) {
    const int GP = F / 4;  // quads per node
    int t = blockIdx.x * blockDim.x + threadIdx.x;
    const int total = N_NODES * GP;
    if (t >= total) return;
    int gi = t % GP;
    int f0 = gi * 4;
    half4_t v = ((const half4_t*)pre)[t];
    float d = dis[t / GP];
    short4_t o;
#pragma unroll
    for (int k = 0; k < 4; k++) {
        int f = f0 + k;
        float y = ((float)v[k] - bn_mean[f]) * bn_rstd[f] * g[f] + be[f];
        y = y > 0.f ? y : 0.f;
        o[k] = q16(y * d);
    }
    ((short4_t*)out)[t] = o;
}

// ---------------- mean pool with FUSED BN3+ReLU (reads fp16 PRE directly) ----------------
#define POOL_CHUNK 32
__global__ void pool_kernel(const _Float16* __restrict__ pre, const int* __restrict__ batch,
                            const float* __restrict__ bn_mean, const float* __restrict__ bn_rstd,
                            const float* __restrict__ g, const float* __restrict__ be,
                            float* __restrict__ pooled, float* __restrict__ cnt) {
    int wave = (blockIdx.x * blockDim.x + threadIdx.x) >> 6;
    int lane = threadIdx.x & 63;  // feature index
    int start = wave * POOL_CHUNK;
    if (start >= N_NODES) return;
    int end = start + POOL_CHUNK;
    if (end > N_NODES) end = N_NODES;
    float A = bn_rstd[lane] * g[lane];
    float B = be[lane] - bn_mean[lane] * A;
    int cur = batch[start];  // wave-uniform -> scalar load
    float acc = 0.f;
    float c = 0.f;
    int i = start;
    for (; i + 4 <= end; i += 4) {
        int b0 = batch[i], b1 = batch[i + 1], b2 = batch[i + 2], b3 = batch[i + 3];
        float v0 = fmaxf(0.f, fmaf((float)pre[(long long)i * 64 + lane], A, B));
        float v1 = fmaxf(0.f, fmaf((float)pre[(long long)(i + 1) * 64 + lane], A, B));
        float v2 = fmaxf(0.f, fmaf((float)pre[(long long)(i + 2) * 64 + lane], A, B));
        float v3 = fmaxf(0.f, fmaf((float)pre[(long long)(i + 3) * 64 + lane], A, B));
        if (b0 != cur) { atomicAdd(&pooled[cur * 64 + lane], acc); if (lane == 0) atomicAdd(&cnt[cur], c); acc = 0.f; c = 0.f; cur = b0; }
        acc += v0; c += 1.f;
        if (b1 != cur) { atomicAdd(&pooled[cur * 64 + lane], acc); if (lane == 0) atomicAdd(&cnt[cur], c); acc = 0.f; c = 0.f; cur = b1; }
        acc += v1; c += 1.f;
        if (b2 != cur) { atomicAdd(&pooled[cur * 64 + lane], acc); if (lane == 0) atomicAdd(&cnt[cur], c); acc = 0.f; c = 0.f; cur = b2; }
        acc += v2; c += 1.f;
        if (b3 != cur) { atomicAdd(&pooled[cur * 64 + lane], acc); if (lane == 0) atomicAdd(&cnt[cur], c); acc = 0.f; c = 0.f; cur = b3; }
        acc += v3; c += 1.f;
    }
    for (; i < end; i++) {
        int b = batch[i];
        if (b != cur) { atomicAdd(&pooled[cur * 64 + lane], acc); if (lane == 0) atomicAdd(&cnt[cur], c); acc = 0.f; c = 0.f; cur = b; }
        acc += fmaxf(0.f, fmaf((float)pre[(long long)i * 64 + lane], A, B)); c += 1.f;
    }
    atomicAdd(&pooled[cur * 64 + lane], acc);
    if (lane == 0) atomicAdd(&cnt[cur], c);
}

// ---------------- final linear ----------------
__global__ void final_kernel(const float* __restrict__ pooled, const float* __restrict__ cnt,
                             const float* __restrict__ fcW, const float* __restrict__ fcb,
                             float* __restrict__ out) {
    int t = blockIdx.x * blockDim.x + threadIdx.x;
    if (t >= B_GRAPHS * 10) return;
    int b = t / 10, j = t % 10;
    float inv = 1.0f / fmaxf(cnt[b], 1.0f);
    float acc = fcb[j];
#pragma unroll
    for (int f = 0; f < 64; f++) acc += pooled[b * 64 + f] * inv * fcW[f * 10 + j];
    out[t] = acc;
}

extern "C" void kernel_launch(void* const* d_in, const int* in_sizes, int n_in,
                              void* d_out, int out_size, void* d_ws, size_t ws_size,
                              hipStream_t stream) {
    const float* x  = (const float*)d_in[0];
    const int* ei   = (const int*)d_in[1];
    const int* batch= (const int*)d_in[2];
    const float* W1 = (const float*)d_in[3];  const float* b1 = (const float*)d_in[4];
    const float* g1 = (const float*)d_in[5];  const float* be1= (const float*)d_in[6];
    const float* W2 = (const float*)d_in[7];  const float* b2 = (const float*)d_in[8];
    const float* g2 = (const float*)d_in[9];  const float* be2= (const float*)d_in[10];
    const float* W3 = (const float*)d_in[11]; const float* b3 = (const float*)d_in[12];
    const float* g3 = (const float*)d_in[13]; const float* be3= (const float*)d_in[14];
    const float* fcW= (const float*)d_in[15]; const float* fcb= (const float*)d_in[16];
    float* out = (float*)d_out;

    const int* row = ei;
    const int* col = ei + N_EDGES;

    // workspace layout — zero region first (one memset): deg, pooled, cnt
    char* wp = (char*)d_ws;
    int*   deg_i      = (int*)wp;                wp += (size_t)N_NODES * 4;
    float* pooled     = (float*)wp;              wp += 64 * 64 * 4;
    float* cnt        = (float*)wp;              wp += 64 * 4;
    const size_t ZERO_BYTES = (size_t)N_NODES * 4 + 64 * 64 * 4 + 64 * 4;
    float* dis        = (float*)wp;              wp += N_NODES * 4;
    int*   row_ptr    = (int*)wp;                wp += N_NODES * 4;
    int*   cursor     = (int*)wp;                wp += N_NODES * 4;
    int*   bsum       = (int*)wp;                wp += 512 * 4;
    int*   bbase      = (int*)wp;                wp += 512 * 4;
    int*   sorted_row = (int*)wp;                wp += (size_t)N_EDGES * 4;
    double* part_s    = (double*)wp;             wp += (size_t)NBMAX * 64 * 8;
    double* part_q    = (double*)wp;             wp += (size_t)NBMAX * 64 * 8;
    float* bn_mean    = (float*)wp;              wp += 64 * 4;
    float* bn_rstd    = (float*)wp;              wp += 64 * 4;
    short* xs4q       = (short*)wp;              wp += (size_t)N_NODES * 4 * 2;
    _Float16* PRE     = (_Float16*)wp;           wp += (size_t)N_NODES * 64 * 2;  // matmul out (fp16)
    short* Hq         = (short*)wp;              wp += (size_t)N_NODES * 32 * 2;  // h1/h2 (int16 fxp, pre-scaled)

    const int BS = 256;

    // ---- one memset for all zero-init state
    hipMemsetAsync(deg_i, 0, ZERO_BYTES, stream);

    // ---- CSR build: direct global-atomic (no bucket partition, no part_edges round-trip)
    deg_hist_kernel<<<cdiv(N_EDGES / 4, BS), BS, 0, stream>>>(col, deg_i);
    bsum_kernel<<<NBS, 256, 0, stream>>>(deg_i, bsum);
    bscan_kernel<<<1, 512, 0, stream>>>(bsum, bbase);
    csr_apply_kernel<<<NBS, 256, 0, stream>>>(deg_i, bbase, row_ptr, cursor, dis, x, xs4q);
    scatter_kernel<<<cdiv(N_EDGES / 4, BS), BS, 0, stream>>>(row, col, cursor, sorted_row);

    // ---- layer 1: fused gather(8B/lane)+matmul 3->16  (NPB=256 -> 391 blocks)
    const int NB1 = cdiv(N_NODES, 256);
    gather_mm_kernel<3, 16, 4, 2><<<NB1, 256, 0, stream>>>(
        row_ptr, deg_i, sorted_row, dis, xs4q, W1, b1, PRE, part_s, part_q);
    bn_finalize_kernel<<<16, 256, 0, stream>>>(part_s, part_q, NB1, bn_mean, bn_rstd);
    bn_relu_kernel<16><<<cdiv((long long)N_NODES * 4, BS), BS, 0, stream>>>(
        PRE, bn_mean, bn_rstd, g1, be1, dis, Hq);  // Hq = h1 * dis (int16 fxp)

    // ---- layer 2: fused gather(16B/lane)+matmul 16->32  (NPB=128 -> 782 blocks)
    const int NB2 = cdiv(N_NODES, 128);
    gather_mm_kernel<16, 32, 16, 4><<<NB2, 256, 0, stream>>>(
        row_ptr, deg_i, sorted_row, dis, Hq, W2, b2, PRE, part_s, part_q);
    bn_finalize_kernel<<<32, 256, 0, stream>>>(part_s, part_q, NB2, bn_mean, bn_rstd);
    bn_relu_kernel<32><<<cdiv((long long)N_NODES * 8, BS), BS, 0, stream>>>(
        PRE, bn_mean, bn_rstd, g2, be2, dis, Hq);  // Hq = h2 * dis (int16 fxp)

    // ---- layer 3: fused gather(16B/lane)+matmul 32->64  (NPB=64 -> 1563 blocks)
    const int NB3 = cdiv(N_NODES, 64);
    gather_mm_kernel<32, 64, 32, 4><<<NB3, 256, 0, stream>>>(
        row_ptr, deg_i, sorted_row, dis, Hq, W3, b3, PRE, part_s, part_q);
    bn_finalize_kernel<<<64, 256, 0, stream>>>(part_s, part_q, NB3, bn_mean, bn_rstd);

    // ---- pool (fused BN3+ReLU) + fc
    pool_kernel<<<cdiv((long long)cdiv(N_NODES, POOL_CHUNK) * 64, BS), BS, 0, stream>>>(
        PRE, batch, bn_mean, bn_rstd, g3, be3, pooled, cnt);
    final_kernel<<<1, B_GRAPHS * 10, 0, stream>>>(pooled, cnt, fcW, fcb, out);
}

// Round 3
// 266.042 us; speedup vs baseline: 1.5026x; 1.5026x over previous
//
#include <hip/hip_runtime.h>

#define N_NODES 100000
#define N_EDGES 1600000
#define B_GRAPHS 64
#define BN_EPS 1e-5
#define NBMAX 3200    // max per-layer stats-partial blocks (L3 uses 1563)

#define NBUCK 256
#define BUCK_NODES 392   // 256*392 = 100352 >= N_NODES; 392 < 512 -> 9-bit local id
#define PART_CHUNK 4096
#define NB_PART 391      // cdiv(N_EDGES, PART_CHUNK)

#define QSCALE 2048.0f            // 2^11 int16 fixed-point scale
#define QINV   4.8828125e-4f      // 2^-11

typedef _Float16 half4_t __attribute__((ext_vector_type(4)));
typedef short short4_t __attribute__((ext_vector_type(4)));
typedef int intv2 __attribute__((ext_vector_type(2)));
typedef int intv4 __attribute__((ext_vector_type(4)));
typedef float floatv4 __attribute__((ext_vector_type(4)));

static inline int cdiv(long long a, int b) { return (int)((a + b - 1) / b); }

__device__ __forceinline__ short q16(float v) {
    int q = __float2int_rn(v * QSCALE);
    q = q > 32767 ? 32767 : (q < -32768 ? -32768 : q);
    return (short)q;
}

// ---------------- phase 1: bucket histogram of col ----------------
__global__ void part_hist_kernel(const int* __restrict__ col, int* __restrict__ bucket_cnt) {
    __shared__ int h[NBUCK];
    for (int i = threadIdx.x; i < NBUCK; i += 256) h[i] = 0;
    __syncthreads();
    long long ebase = (long long)blockIdx.x * PART_CHUNK;
    int n = (N_EDGES - ebase < PART_CHUNK) ? (int)(N_EDGES - ebase) : PART_CHUNK;
    for (int i = threadIdx.x; i < n; i += 256)
        atomicAdd(&h[col[ebase + i] / BUCK_NODES], 1);
    __syncthreads();
    for (int i = threadIdx.x; i < NBUCK; i += 256)
        if (h[i]) atomicAdd(&bucket_cnt[i], h[i]);
}

// ---------------- phase 2: scan bucket counts -> base & cursor ----------------
__global__ void part_scan_kernel(const int* __restrict__ bucket_cnt, int* __restrict__ bucket_base,
                                 int* __restrict__ bucket_cur) {
    __shared__ int s[NBUCK];
    int t = threadIdx.x;
    int v = bucket_cnt[t];
    s[t] = v;
    __syncthreads();
    for (int off = 1; off < NBUCK; off <<= 1) {
        int u = (t >= off) ? s[t - off] : 0;
        __syncthreads();
        s[t] += u;
        __syncthreads();
    }
    bucket_base[t] = s[t] - v;  // exclusive
    bucket_cur[t] = s[t] - v;
}

// ---------------- phase 3: partition edges; pack (row,local_col) into one uint ----------------
// Edge order nondeterministic; downstream sums are order-INDEPENDENT (int accumulation).
__global__ void part_scatter_kernel(const int* __restrict__ row, const int* __restrict__ col,
                                    int* __restrict__ bucket_cur, unsigned* __restrict__ part_edges) {
    __shared__ int h[NBUCK];
    __shared__ int base_s[NBUCK];
    __shared__ int cur_s[NBUCK];
    long long ebase = (long long)blockIdx.x * PART_CHUNK;
    int n = (N_EDGES - ebase < PART_CHUNK) ? (int)(N_EDGES - ebase) : PART_CHUNK;
    for (int i = threadIdx.x; i < NBUCK; i += 256) h[i] = 0;
    __syncthreads();
    for (int i = threadIdx.x; i < n; i += 256)
        atomicAdd(&h[col[ebase + i] / BUCK_NODES], 1);
    __syncthreads();
    for (int i = threadIdx.x; i < NBUCK; i += 256) {
        int c = h[i];
        base_s[i] = c ? atomicAdd(&bucket_cur[i], c) : 0;
        cur_s[i] = 0;
    }
    __syncthreads();
    for (int i = threadIdx.x; i < n; i += 256) {
        int r = row[ebase + i], c = col[ebase + i];
        int bkt = c / BUCK_NODES;
        int p = base_s[bkt] + atomicAdd(&cur_s[bkt], 1);
        part_edges[p] = ((unsigned)r << 9) | (unsigned)(c - bkt * BUCK_NODES);
    }
}

// ---------------- phase 4: per-bucket CSR build + fused scale_x (int16 fixed-point, pad 3->4) ----------------
__global__ void csr_build_kernel(const int* __restrict__ bucket_base, const unsigned* __restrict__ part_edges,
                                 int* __restrict__ row_ptr, int* __restrict__ deg,
                                 float* __restrict__ dis, int* __restrict__ sorted_row,
                                 const float* __restrict__ x, short* __restrict__ xs4) {
    __shared__ int hist[BUCK_NODES];  // histogram, then reused as scatter cursors
    __shared__ int tsum[256];
    int b = blockIdx.x;
    int t = threadIdx.x;
    int nbase = b * BUCK_NODES;
    int ebase = bucket_base[b];
    int eend = (b == NBUCK - 1) ? N_EDGES : bucket_base[b + 1];
    int ne = eend - ebase;
    for (int i = t; i < BUCK_NODES; i += 256) hist[i] = 0;
    __syncthreads();
    for (int i = t; i < ne; i += 256)
        atomicAdd(&hist[part_edges[ebase + i] & 511u], 1);
    __syncthreads();
    int a0 = 0, a1 = 0;
    if (t < BUCK_NODES / 2) { a0 = hist[2 * t]; a1 = hist[2 * t + 1]; tsum[t] = a0 + a1; }
    else tsum[t] = 0;
    __syncthreads();
    for (int off = 1; off < 256; off <<= 1) {
        int u = (t >= off) ? tsum[t - off] : 0;
        __syncthreads();
        tsum[t] += u;
        __syncthreads();
    }
    if (t < BUCK_NODES / 2) {
        int excl = tsum[t] - (a0 + a1);
        hist[2 * t] = excl;
        hist[2 * t + 1] = excl + a0;
        int n0 = nbase + 2 * t, n1 = n0 + 1;
        if (n0 < N_NODES) {
            row_ptr[n0] = ebase + excl;
            deg[n0] = a0;
            dis[n0] = rsqrtf((float)a0 + 1.0f);
        }
        if (n1 < N_NODES) {
            row_ptr[n1] = ebase + excl + a0;
            deg[n1] = a1;
            dis[n1] = rsqrtf((float)a1 + 1.0f);
        }
    }
    __syncthreads();
    for (int i = t; i < ne; i += 256) {
        unsigned e = part_edges[ebase + i];
        int p = atomicAdd(&hist[e & 511u], 1);
        sorted_row[ebase + p] = (int)(e >> 9);
    }
    // fused scale_x (int16 fixed-point) for this bucket's nodes
    for (int i = t; i < BUCK_NODES; i += 256) {
        int n = nbase + i;
        if (n < N_NODES) {
            float d = dis[n];
            short4_t v;
            v.x = q16(x[n * 3 + 0] * d);
            v.y = q16(x[n * 3 + 1] * d);
            v.z = q16(x[n * 3 + 2] * d);
            v.w = 0;
            ((short4_t*)xs4)[n] = v;
        }
    }
}

// ---------------- FUSED: CSR gather (16B int16 vector loads, pure-int accumulation)
//                  -> LDS -> matmul (W in regs, b128 broadcast agg reads) -> fp16 pre + fp64 stats
// Activations stored pre-quantized int16; integer accumulation -> order-independent (deterministic).
// WPL = 32-bit words per lane of gather payload (2 -> int2/8B, 4 -> int4/16B).
// UNROLL=8: 8 loads in flight/lane (64-128B) — gather is latency-bound (r0: VALUBusy 34%,
// occupancy grid-capped at ~75%, VGPR headroom) so deeper MLP is the lever.
template <int WPL> struct VecSel;
template <> struct VecSel<2> { using type = intv2; };
template <> struct VecSel<4> { using type = intv4; };

template <int IN, int OUT, int INSTRIDE, int WPL>
__global__ void gather_mm_kernel(const int* __restrict__ row_ptr, const int* __restrict__ deg,
                                 const int* __restrict__ sorted_row, const float* __restrict__ dis,
                                 const short* __restrict__ hs, const float* __restrict__ W,
                                 const float* __restrict__ b, _Float16* __restrict__ pre,
                                 double* __restrict__ part_s, double* __restrict__ part_q) {
    using V = typename VecSel<WPL>::type;
    const int FPL = 2 * WPL;          // int16 features per lane
    const int LPN = INSTRIDE / FPL;   // lanes per node (L1:1, L2:2, L3:4)
    const int NPW = 64 / LPN;         // nodes per wave
    const int NPB = 4 * NPW;          // nodes per block (L1:256, L2:128, L3:64)
    const int UNROLL = 8;
    __shared__ __align__(16) float lds_agg[NPB * INSTRIDE];
    __shared__ double s_s[256];
    __shared__ double s_q[256];
    int tid = threadIdx.x;
    int wv = tid >> 6, lane = tid & 63;
    int jn = wv * NPW + lane / LPN;   // node index within block
    int p = lane % LPN;               // feature-slice index
    int n = blockIdx.x * NPB + jn;
    if (n < N_NODES) {
        int start = row_ptr[n];
        int d = deg[n];
        const int* sr = sorted_row + start;
        const V* hv = (const V*)hs;
        V v = hv[n * LPN + p];        // self-loop term; 32-bit index (fits: N*LPN < 2^31)
        int acc[FPL];
#pragma unroll
        for (int w = 0; w < WPL; w++) {
            acc[2 * w] = (int)(short)v[w];
            acc[2 * w + 1] = v[w] >> 16;
        }
        int j = 0;
        for (; j + UNROLL <= d; j += UNROLL) {
            V a[UNROLL];
#pragma unroll
            for (int u = 0; u < UNROLL; u++) a[u] = hv[sr[j + u] * LPN + p];
#pragma unroll
            for (int u = 0; u < UNROLL; u++) {
#pragma unroll
                for (int w = 0; w < WPL; w++) {
                    acc[2 * w] += (int)(short)a[u][w];
                    acc[2 * w + 1] += a[u][w] >> 16;
                }
            }
        }
        for (; j < d; j++) {
            V a = hv[sr[j] * LPN + p];
#pragma unroll
            for (int w = 0; w < WPL; w++) {
                acc[2 * w] += (int)(short)a[w];
                acc[2 * w + 1] += a[w] >> 16;
            }
        }
        float dn = dis[n] * QINV;
        float* dst = &lds_agg[(jn * LPN + p) * FPL];  // 16B/32B aligned -> ds_write_b128
#pragma unroll
        for (int k = 0; k < FPL; k++) dst[k] = dn * (float)acc[k];
    }
    __syncthreads();

    // ---- matmul + stats phase (deterministic: fixed order over deterministic agg)
    // W column held in registers (coalesced global loads, L2-hot); lds_agg read as
    // wave-uniform float4 broadcasts -> ~5x fewer LDS ops than scalar form.
    const int NG = 256 / OUT;  // node groups
    int o = tid % OUT;
    int g = tid / OUT;
    float wreg[IN];
#pragma unroll
    for (int k = 0; k < IN; k++) wreg[k] = W[k * OUT + o];
    float bo = b[o];
    double my_s = 0.0, my_q = 0.0;
    for (int j2 = g; j2 < NPB; j2 += NG) {
        int nn = blockIdx.x * NPB + j2;
        if (nn < N_NODES) {
            float acc = bo;
            const floatv4* src = (const floatv4*)&lds_agg[j2 * INSTRIDE];
#pragma unroll
            for (int q = 0; q < INSTRIDE / 4; q++) {
                floatv4 vq = src[q];
#pragma unroll
                for (int c = 0; c < 4; c++) {
                    if (4 * q + c < IN) acc += vq[c] * wreg[4 * q + c];
                }
            }
            _Float16 hq = (_Float16)acc;
            pre[nn * OUT + o] = hq;
            float fq = (float)hq;  // stats on quantized values
            my_s += (double)fq;
            my_q += (double)fq * (double)fq;
        }
    }
    s_s[tid] = my_s;
    s_q[tid] = my_q;
    __syncthreads();
    if (tid < OUT) {
        double ts = 0.0, tq = 0.0;
        for (int k = tid; k < 256; k += OUT) { ts += s_s[k]; tq += s_q[k]; }
        part_s[(long long)tid * NBMAX + blockIdx.x] = ts;
        part_q[(long long)tid * NBMAX + blockIdx.x] = tq;
    }
}

// ---------------- finalize BN stats: one block per feature, variable #partials ----------------
__global__ void bn_finalize_kernel(const double* __restrict__ part_s, const double* __restrict__ part_q,
                                   int nb, float* __restrict__ bn_mean, float* __restrict__ bn_rstd) {
    __shared__ double s_s[256];
    __shared__ double s_q[256];
    int o = blockIdx.x;
    int t = threadIdx.x;
    double ms = 0.0, mq = 0.0;
    for (int k = t; k < nb; k += 256) {
        ms += part_s[(long long)o * NBMAX + k];
        mq += part_q[(long long)o * NBMAX + k];
    }
    s_s[t] = ms;
    s_q[t] = mq;
    __syncthreads();
    for (int off = 128; off > 0; off >>= 1) {
        if (t < off) { s_s[t] += s_s[t + off]; s_q[t] += s_q[t + off]; }
        __syncthreads();
    }
    if (t == 0) {
        double mean = s_s[0] / (double)N_NODES;
        double var = s_q[0] / (double)N_NODES - mean * mean;
        bn_mean[o] = (float)mean;
        bn_rstd[o] = (float)(1.0 / sqrt(var + BN_EPS));
    }
}

// ---------------- BN apply + ReLU + dis pre-scale; fp16 in, INT16 fixed-point out ----------------
template <int F>
__global__ void bn_relu_kernel(const _Float16* __restrict__ pre, const float* __restrict__ bn_mean,
                               const float* __restrict__ bn_rstd, const float* __restrict__ g,
                               const float* __restrict__ be, const float* __restrict__ dis,
                               short* __restrict__ out) {
    const int GP = F / 4;  // quads per node
    int t = blockIdx.x * blockDim.x + threadIdx.x;
    const int total = N_NODES * GP;
    if (t >= total) return;
    int gi = t % GP;
    int f0 = gi * 4;
    half4_t v = ((const half4_t*)pre)[t];
    float d = dis[t / GP];
    short4_t o;
#pragma unroll
    for (int k = 0; k < 4; k++) {
        int f = f0 + k;
        float y = ((float)v[k] - bn_mean[f]) * bn_rstd[f] * g[f] + be[f];
        y = y > 0.f ? y : 0.f;
        o[k] = q16(y * d);
    }
    ((short4_t*)out)[t] = o;
}

// ---------------- mean pool with FUSED BN3+ReLU (reads fp16 PRE directly) ----------------
#define POOL_CHUNK 32
__global__ void pool_kernel(const _Float16* __restrict__ pre, const int* __restrict__ batch,
                            const float* __restrict__ bn_mean, const float* __restrict__ bn_rstd,
                            const float* __restrict__ g, const float* __restrict__ be,
                            float* __restrict__ pooled, float* __restrict__ cnt) {
    int wave = (blockIdx.x * blockDim.x + threadIdx.x) >> 6;
    int lane = threadIdx.x & 63;  // feature index
    int start = wave * POOL_CHUNK;
    if (start >= N_NODES) return;
    int end = start + POOL_CHUNK;
    if (end > N_NODES) end = N_NODES;
    float A = bn_rstd[lane] * g[lane];
    float B = be[lane] - bn_mean[lane] * A;
    int cur = batch[start];  // wave-uniform -> scalar load
    float acc = 0.f;
    float c = 0.f;
    int i = start;
    for (; i + 4 <= end; i += 4) {
        int b0 = batch[i], b1 = batch[i + 1], b2 = batch[i + 2], b3 = batch[i + 3];
        float v0 = fmaxf(0.f, fmaf((float)pre[(long long)i * 64 + lane], A, B));
        float v1 = fmaxf(0.f, fmaf((float)pre[(long long)(i + 1) * 64 + lane], A, B));
        float v2 = fmaxf(0.f, fmaf((float)pre[(long long)(i + 2) * 64 + lane], A, B));
        float v3 = fmaxf(0.f, fmaf((float)pre[(long long)(i + 3) * 64 + lane], A, B));
        if (b0 != cur) { atomicAdd(&pooled[cur * 64 + lane], acc); if (lane == 0) atomicAdd(&cnt[cur], c); acc = 0.f; c = 0.f; cur = b0; }
        acc += v0; c += 1.f;
        if (b1 != cur) { atomicAdd(&pooled[cur * 64 + lane], acc); if (lane == 0) atomicAdd(&cnt[cur], c); acc = 0.f; c = 0.f; cur = b1; }
        acc += v1; c += 1.f;
        if (b2 != cur) { atomicAdd(&pooled[cur * 64 + lane], acc); if (lane == 0) atomicAdd(&cnt[cur], c); acc = 0.f; c = 0.f; cur = b2; }
        acc += v2; c += 1.f;
        if (b3 != cur) { atomicAdd(&pooled[cur * 64 + lane], acc); if (lane == 0) atomicAdd(&cnt[cur], c); acc = 0.f; c = 0.f; cur = b3; }
        acc += v3; c += 1.f;
    }
    for (; i < end; i++) {
        int b = batch[i];
        if (b != cur) { atomicAdd(&pooled[cur * 64 + lane], acc); if (lane == 0) atomicAdd(&cnt[cur], c); acc = 0.f; c = 0.f; cur = b; }
        acc += fmaxf(0.f, fmaf((float)pre[(long long)i * 64 + lane], A, B)); c += 1.f;
    }
    atomicAdd(&pooled[cur * 64 + lane], acc);
    if (lane == 0) atomicAdd(&cnt[cur], c);
}

// ---------------- final linear ----------------
__global__ void final_kernel(const float* __restrict__ pooled, const float* __restrict__ cnt,
                             const float* __restrict__ fcW, const float* __restrict__ fcb,
                             float* __restrict__ out) {
    int t = blockIdx.x * blockDim.x + threadIdx.x;
    if (t >= B_GRAPHS * 10) return;
    int b = t / 10, j = t % 10;
    float inv = 1.0f / fmaxf(cnt[b], 1.0f);
    float acc = fcb[j];
#pragma unroll
    for (int f = 0; f < 64; f++) acc += pooled[b * 64 + f] * inv * fcW[f * 10 + j];
    out[t] = acc;
}

extern "C" void kernel_launch(void* const* d_in, const int* in_sizes, int n_in,
                              void* d_out, int out_size, void* d_ws, size_t ws_size,
                              hipStream_t stream) {
    const float* x  = (const float*)d_in[0];
    const int* ei   = (const int*)d_in[1];
    const int* batch= (const int*)d_in[2];
    const float* W1 = (const float*)d_in[3];  const float* b1 = (const float*)d_in[4];
    const float* g1 = (const float*)d_in[5];  const float* be1= (const float*)d_in[6];
    const float* W2 = (const float*)d_in[7];  const float* b2 = (const float*)d_in[8];
    const float* g2 = (const float*)d_in[9];  const float* be2= (const float*)d_in[10];
    const float* W3 = (const float*)d_in[11]; const float* b3 = (const float*)d_in[12];
    const float* g3 = (const float*)d_in[13]; const float* be3= (const float*)d_in[14];
    const float* fcW= (const float*)d_in[15]; const float* fcb= (const float*)d_in[16];
    float* out = (float*)d_out;

    const int* row = ei;
    const int* col = ei + N_EDGES;

    // workspace layout — zero region first (one memset): bucket_cnt, pooled, cnt
    char* wp = (char*)d_ws;
    int*   bucket_cnt = (int*)wp;                wp += NBUCK * 4;
    float* pooled     = (float*)wp;              wp += 64 * 64 * 4;
    float* cnt        = (float*)wp;              wp += 64 * 4;
    const size_t ZERO_BYTES = NBUCK * 4 + 64 * 64 * 4 + 64 * 4;
    float* dis        = (float*)wp;              wp += N_NODES * 4;
    int*   deg_i      = (int*)wp;                wp += N_NODES * 4;
    int*   row_ptr    = (int*)wp;                wp += N_NODES * 4;
    int*   bucket_base= (int*)wp;                wp += NBUCK * 4;
    int*   bucket_cur = (int*)wp;                wp += NBUCK * 4;
    int*   sorted_row = (int*)wp;                wp += (size_t)N_EDGES * 4;
    unsigned* part_edges = (unsigned*)wp;        wp += (size_t)N_EDGES * 4;
    double* part_s    = (double*)wp;             wp += (size_t)NBMAX * 64 * 8;
    double* part_q    = (double*)wp;             wp += (size_t)NBMAX * 64 * 8;
    float* bn_mean    = (float*)wp;              wp += 64 * 4;
    float* bn_rstd    = (float*)wp;              wp += 64 * 4;
    short* xs4q       = (short*)wp;              wp += (size_t)N_NODES * 4 * 2;
    _Float16* PRE     = (_Float16*)wp;           wp += (size_t)N_NODES * 64 * 2;  // matmul out (fp16)
    short* Hq         = (short*)wp;              wp += (size_t)N_NODES * 32 * 2;  // h1/h2 (int16 fxp, pre-scaled)

    const int BS = 256;

    // ---- one memset for all zero-init state
    hipMemsetAsync(bucket_cnt, 0, ZERO_BYTES, stream);

    // ---- CSR build: bucketed two-phase (order-nondeterministic — harmless); emits xs4q
    part_hist_kernel<<<NB_PART, 256, 0, stream>>>(col, bucket_cnt);
    part_scan_kernel<<<1, NBUCK, 0, stream>>>(bucket_cnt, bucket_base, bucket_cur);
    part_scatter_kernel<<<NB_PART, 256, 0, stream>>>(row, col, bucket_cur, part_edges);
    csr_build_kernel<<<NBUCK, 256, 0, stream>>>(bucket_base, part_edges, row_ptr, deg_i, dis, sorted_row, x, xs4q);

    // ---- layer 1: fused gather(8B/lane)+matmul 3->16  (NPB=256 -> 391 blocks)
    const int NB1 = cdiv(N_NODES, 256);
    gather_mm_kernel<3, 16, 4, 2><<<NB1, 256, 0, stream>>>(
        row_ptr, deg_i, sorted_row, dis, xs4q, W1, b1, PRE, part_s, part_q);
    bn_finalize_kernel<<<16, 256, 0, stream>>>(part_s, part_q, NB1, bn_mean, bn_rstd);
    bn_relu_kernel<16><<<cdiv((long long)N_NODES * 4, BS), BS, 0, stream>>>(
        PRE, bn_mean, bn_rstd, g1, be1, dis, Hq);  // Hq = h1 * dis (int16 fxp)

    // ---- layer 2: fused gather(16B/lane)+matmul 16->32  (NPB=128 -> 782 blocks)
    const int NB2 = cdiv(N_NODES, 128);
    gather_mm_kernel<16, 32, 16, 4><<<NB2, 256, 0, stream>>>(
        row_ptr, deg_i, sorted_row, dis, Hq, W2, b2, PRE, part_s, part_q);
    bn_finalize_kernel<<<32, 256, 0, stream>>>(part_s, part_q, NB2, bn_mean, bn_rstd);
    bn_relu_kernel<32><<<cdiv((long long)N_NODES * 8, BS), BS, 0, stream>>>(
        PRE, bn_mean, bn_rstd, g2, be2, dis, Hq);  // Hq = h2 * dis (int16 fxp)

    // ---- layer 3: fused gather(16B/lane)+matmul 32->64  (NPB=64 -> 1563 blocks)
    const int NB3 = cdiv(N_NODES, 64);
    gather_mm_kernel<32, 64, 32, 4><<<NB3, 256, 0, stream>>>(
        row_ptr, deg_i, sorted_row, dis, Hq, W3, b3, PRE, part_s, part_q);
    bn_finalize_kernel<<<64, 256, 0, stream>>>(part_s, part_q, NB3, bn_mean, bn_rstd);

    // ---- pool (fused BN3+ReLU) + fc
    pool_kernel<<<cdiv((long long)cdiv(N_NODES, POOL_CHUNK) * 64, BS), BS, 0, stream>>>(
        PRE, batch, bn_mean, bn_rstd, g3, be3, pooled, cnt);
    final_kernel<<<1, B_GRAPHS * 10, 0, stream>>>(pooled, cnt, fcW, fcb, out);
}